// Round 17
// baseline (4111.444 us; speedup 1.0000x reference)
//
#include <hip/hip_runtime.h>
#include <hip/hip_bf16.h>
#include <stdint.h>
#include <math.h>

// ROUND-17: OUTPUT DTYPE FIX — d_out is FLOAT32 (the reference's output
// dtype), not bf16. All 16 prior rounds wrote packed bf16 into an fp32
// buffer -> checker read garbage -> uniform ~6.8 decorrelation regardless
// of structure (explains every collision + r0's max|G|=4.97 + threshold
// = 2% of it). Formula: r6's brute-force literal implementation of the
// printed reference (cross-validated bit-identical by 3 independent codes).
//
// Inputs (fp32): state [32][256][512], obs [32][256][256], Qp [512][256],
// Wq [256][256], bq [256], Wk [256][256], bk [256].
// Output (fp32): new_state [32][256][512] ++ atten [32][512][768].
// d_ws holds P [32][256] (head-summed state-side softmax weights).

// ---------------------------------------------------------------------------
// K1: brute-force p (r6 formula, printed reference).  32 blocks x 256 thr.
// l = 256 + j:
//   q[d]  = sum_e (Qp[l,e] + pe[b,e]) * Wq[d,e] + bq[d]
//   ks[d] = sum_e (state[b,e,l] - mu_s + pe[b,e]) * Wk[d,e] + bk[d]  (s=l)
//   ko[d] = sum_e (obs[b,e,j]  - mu_o + pe[b,e]) * Wk[d,e] + bk[d]  (s=l+256)
//   per-head dots / sqrt(32); p = mean_h softmax2(c1,c2)[0].
__global__ void k_p_simple(const float* __restrict__ state,
                           const float* __restrict__ obs,
                           const float* __restrict__ Qp,
                           const float* __restrict__ Wq,
                           const float* __restrict__ bq,
                           const float* __restrict__ Wk,
                           const float* __restrict__ bk,
                           float* __restrict__ P) {
  int b = blockIdx.x;
  int j = threadIdx.x;
  int l = 256 + j;

  __shared__ float pe[256];
  {
    int e = j;
    int k2 = e & ~1;                    // arange value 2k
    float div = expf((float)k2 * (-9.210340371976184f / 256.0f)); // -ln(1e4)/256
    float a = (float)b * div;
    pe[e] = (e & 1) ? cosf(a) : sinf(a);
  }
  __syncthreads();

  const float* sb = state + (size_t)b * 131072;   // [e][512]
  const float* ob = obs   + (size_t)b * 65536;    // [e][256]

  float mu_s = 0.f, mu_o = 0.f;
  for (int e = 0; e < 256; ++e) {
    mu_s += sb[(size_t)e * 512 + l];
    mu_o += ob[(size_t)e * 256 + j];
  }
  mu_s *= (1.f / 256.f);
  mu_o *= (1.f / 256.f);

  const float* qp_row = Qp + (size_t)l * 256;

  float psum = 0.f;
  for (int h = 0; h < 8; ++h) {
    float c1 = 0.f, c2 = 0.f;
    for (int r = 0; r < 32; ++r) {
      int d = h * 32 + r;
      const float* wq_row = Wq + (size_t)d * 256;
      const float* wk_row = Wk + (size_t)d * 256;
      float q  = bq[d];
      float ks = bk[d];
      float ko = bk[d];
      for (int e = 0; e < 256; ++e) {
        float pe_e = pe[e];
        q  += (qp_row[e] + pe_e) * wq_row[e];
        ks += (sb[(size_t)e * 512 + l] - mu_s + pe_e) * wk_row[e];
        ko += (ob[(size_t)e * 256 + j] - mu_o + pe_e) * wk_row[e];
      }
      c1 += q * ks;
      c2 += q * ko;
    }
    c1 *= 0.17677669529663687f;         // 1/sqrt(32)
    c2 *= 0.17677669529663687f;
    float m  = fmaxf(c1, c2);
    float e1 = expf(c1 - m), e2 = expf(c2 - m);
    psum += e1 / (e1 + e2);             // softmax share of the s=l (state) key
  }
  P[b * 256 + j] = psum;                // sum over heads; consumers * 0.125
}

// ---------------------------------------------------------------------------
// K2: new_state [b,e,l], FP32.  8192 blocks = (b,e) rows; float2 per thread.
// l < 256: state copy;  l >= 256: p*state_l + (1-p)*obs_{l-256}.
__global__ void k_ns(const float* __restrict__ state, const float* __restrict__ obs,
                     const float* __restrict__ P, float* __restrict__ out) {
  int bid = blockIdx.x, t = threadIdx.x;
  int b = bid >> 8;
  const float2* srow = (const float2*)(state + (size_t)bid * 512);
  const float2* orow = (const float2*)(obs + (size_t)bid * 256);
  float2* orow_out = (float2*)(out + (size_t)bid * 512);
  float2 sv = srow[t];                  // cols l = 2t, 2t+1
  if (t < 128) {                        // l < 256: identity
    orow_out[t] = sv;
  } else {                              // l >= 256: blend with obs col l-256
    int j0 = 2 * t - 256;
    float2 ov = orow[t - 128];
    float p0 = P[b * 256 + j0] * 0.125f;
    float p1 = P[b * 256 + j0 + 1] * 0.125f;
    float2 r;
    r.x = p0 * sv.x + (1.f - p0) * ov.x;
    r.y = p1 * sv.y + (1.f - p1) * ov.y;
    orow_out[t] = r;
  }
}

// ---------------------------------------------------------------------------
// K3: atten [32][512 l][768 s], FP32.  49152 blocks; one float per thread.
// l < 256: 1 at s=l.  l >= 256: p at s=l, 1-p at s=l+256.  Else 0.
__global__ void k_atten(const float* __restrict__ P, float* __restrict__ out) {
  int g = blockIdx.x * 256 + threadIdx.x;   // 0..12582911
  int r = g / 768, s = g - r * 768;
  int b = r >> 9, l = r & 511;
  float v = 0.f;
  if (l < 256) {
    if (s == l) v = 1.0f;
  } else {
    if (s == l) v = P[b * 256 + (l - 256)] * 0.125f;
    else if (s == l + 256) v = 1.0f - P[b * 256 + (l - 256)] * 0.125f;
  }
  out[g] = v;
}

extern "C" void kernel_launch(void* const* d_in, const int* in_sizes, int n_in,
                              void* d_out, int out_size, void* d_ws, size_t ws_size,
                              hipStream_t stream) {
  const float *state = nullptr, *obs = nullptr, *Qp = nullptr;
  const float *Wq = nullptr, *Wk = nullptr, *bq = nullptr, *bk = nullptr;
  for (int i = 0; i < n_in; ++i) {
    int s = in_sizes[i];
    const float* p = (const float*)d_in[i];
    if      (s == 4194304) state = p;
    else if (s == 2097152) obs = p;
    else if (s == 131072)  Qp = p;
    else if (s == 65536)   { if (!Wq) Wq = p; else Wk = p; }
    else if (s == 256)     { if (!bq) bq = p; else bk = p; }
  }
  float* out = (float*)d_out;           // FP32 output (reference dtype)
  float* P   = (float*)d_ws;            // [32][256]

  k_p_simple<<<32,    256, 0, stream>>>(state, obs, Qp, Wq, bq, Wk, bk, P);
  k_ns      <<<8192,  256, 0, stream>>>(state, obs, P, out);
  k_atten   <<<49152, 256, 0, stream>>>(P, out + 4194304);
}

// Round 18
// 169.831 us; speedup vs baseline: 24.2090x; 24.2090x over previous
//
#include <hip/hip_runtime.h>
#include <stdint.h>
#include <math.h>

// Validated semantics (r17 green): printed reference, fp32 in, FP32 OUT.
//   p[b,j] = mean_h softmax2(c1,c2)[0],  c1-c2 = delta/sqrt(32),
//   delta[j,b,h] = sum_e D_e * (U[h,e,j] + V[b,h,e]),
//     D_e = (state[b,e,256+j]-mu_s) - (obs[b,e,j]-mu_o)   (pe, bk cancel)
//     U[h,e,j] = sum_{d in h} QwT[d,j]*Wk[d,e],  QwT = Qp[256+j]@Wq^T
//     V[b,h,e] = sum_{d in h} (Pq[b,d]+bq[d])*Wk[d,e],  Pq = pe[b]@Wq^T
//   new_state[b,e,l<256]=state; l>=256: p*state_l+(1-p)*obs_{l-256}
//   atten[b,l,s]: l<256 -> 1 at s=l; else p at s=l, 1-p at s=l+256.
// Factorization numerically validated: r2(ws-scratch)=r3=r4=r6 bit-identical
// => same P as the brute force AND ws_size >= 3.3 MB proven.

// d_ws layout (floats)
#define WS_P    0        // [32 b][256 j]  sum_h sigmoid
#define WS_PE   8192     // [32 b][256 e]
#define WS_MUS  16384    // [32 b][256 j]
#define WS_MUO  24576    // [32 b][256 j]
#define WS_QWT  32768    // [256 d][256 j]
#define WS_PQ   98304    // [32 b][256 d]
#define WS_U    106496   // [8 h][256 e][256 j]
#define WS_V    630784   // [32 b][8 h][256 e]
// end 696320 floats = 2.72 MB

// ---------------------------------------------------------------------------
// K1: mu_s, mu_o, pe, zero P.  66 blocks x 256.
__global__ void k_prep(const float* __restrict__ state, const float* __restrict__ obs,
                       float* __restrict__ ws) {
  int bid = blockIdx.x, t = threadIdx.x;
  if (bid < 32) {                       // mu_s[b][j] over col l = 256+j
    float acc = 0.f;
    const float* p = state + (size_t)bid * 131072 + 256 + t;
    for (int e = 0; e < 256; ++e) acc += p[(size_t)e * 512];
    ws[WS_MUS + bid * 256 + t] = acc * (1.f / 256.f);
  } else if (bid < 64) {                // mu_o[b][j]
    int b = bid - 32; float acc = 0.f;
    const float* p = obs + (size_t)b * 65536 + t;
    for (int e = 0; e < 256; ++e) acc += p[(size_t)e * 256];
    ws[WS_MUO + b * 256 + t] = acc * (1.f / 256.f);
  } else if (bid == 64) {               // pe[pos=b][d=e]
    for (int i = t; i < 8192; i += 256) {
      int b = i >> 8, e = i & 255, k2 = e & ~1;
      float div = expf((float)k2 * (-9.210340371976184f / 256.f));
      float a = (float)b * div;
      ws[WS_PE + i] = (e & 1) ? cosf(a) : sinf(a);
    }
  } else {                              // zero P (ws is re-poisoned each call)
    for (int i = t; i < 8192; i += 256) ws[WS_P + i] = 0.f;
  }
}

// ---------------------------------------------------------------------------
// K2: QwT[d][j] = sum_e Qp[256+j][e]*Wq[d][e];  Pq[b][d] = sum_e pe[b][e]*Wq[d][e]
// 288 blocks x 256 (r3 design, proven).
__global__ void k_qwpq(const float* __restrict__ Qp, const float* __restrict__ Wq,
                       float* __restrict__ ws) {
  __shared__ float row[256];
  int bid = blockIdx.x, t = threadIdx.x;
  if (bid < 256) {
    int d = bid;
    row[t] = Wq[(size_t)d * 256 + t];
    __syncthreads();
    const float* qrow = Qp + (size_t)(256 + t) * 256;   // t = j
    float acc = 0.f;
    for (int e = 0; e < 256; ++e) acc += qrow[e] * row[e];
    ws[WS_QWT + d * 256 + t] = acc;
  } else {
    int b = bid - 256;
    row[t] = ws[WS_PE + b * 256 + t];
    __syncthreads();
    const float* wrow = Wq + (size_t)t * 256;           // t = d
    float acc = 0.f;
    for (int e = 0; e < 256; ++e) acc += row[e] * wrow[e];
    ws[WS_PQ + b * 256 + t] = acc;
  }
}

// ---------------------------------------------------------------------------
// K3: U[h][e][j] and V[b][h][e].  2304 blocks x 256.
__global__ void k_uv(const float* __restrict__ Wk, const float* __restrict__ bq,
                     float* __restrict__ ws) {
  int bid = blockIdx.x, t = threadIdx.x;
  if (bid < 2048) {
    int h = bid >> 8, e = bid & 255;
    float acc = 0.f;
#pragma unroll 8
    for (int dd = 0; dd < 32; ++dd) {
      int d = h * 32 + dd;
      acc += ws[WS_QWT + d * 256 + t] * Wk[(size_t)d * 256 + e];
    }
    ws[WS_U + ((h << 8) + e) * 256 + t] = acc;
  } else {
    int idx = bid - 2048, b = idx >> 3, h = idx & 7;
    float acc = 0.f;
#pragma unroll 8
    for (int dd = 0; dd < 32; ++dd) {
      int d = h * 32 + dd;
      acc += (ws[WS_PQ + b * 256 + d] + bq[d]) * Wk[(size_t)d * 256 + t];
    }
    ws[WS_V + ((b << 3) + h) * 256 + t] = acc;
  }
}

// ---------------------------------------------------------------------------
// K4: delta + sigmoid accumulate.  256 blocks = (b,h) x 256 threads = j.
__global__ void k_delta(const float* __restrict__ state, const float* __restrict__ obs,
                        float* __restrict__ ws) {
  int b = blockIdx.x >> 3, h = blockIdx.x & 7;
  int j = threadIdx.x;
  __shared__ float vsh[256];
  vsh[j] = ws[WS_V + ((b << 3) + h) * 256 + j];
  __syncthreads();
  float mdiff = ws[WS_MUS + b * 256 + j] - ws[WS_MUO + b * 256 + j];
  const float* Uh = ws + WS_U + (h << 16);
  const float* sp = state + (size_t)b * 131072 + 256 + j;
  const float* op = obs + (size_t)b * 65536 + j;
  float acc = 0.f;
#pragma unroll 4
  for (int e = 0; e < 256; ++e) {
    float dv = sp[(size_t)e * 512] - op[(size_t)e * 256] - mdiff;
    acc += dv * (Uh[(e << 8) + j] + vsh[e]);
  }
  float ph = 1.f / (1.f + __expf(-acc * 0.17677669529663687f)); // sigma(delta/sqrt(32))
  atomicAdd(&ws[WS_P + b * 256 + j], ph);
}

// ---------------------------------------------------------------------------
// K5: new_state [b,e,l] FP32.  8192 blocks = (b,e) rows; float2 per thread.
__global__ void k_ns(const float* __restrict__ state, const float* __restrict__ obs,
                     const float* __restrict__ ws, float* __restrict__ out) {
  int bid = blockIdx.x, t = threadIdx.x;
  int b = bid >> 8;
  const float2* srow = (const float2*)(state + (size_t)bid * 512);
  const float2* orow = (const float2*)(obs + (size_t)bid * 256);
  float2* wrow = (float2*)(out + (size_t)bid * 512);
  float2 sv = srow[t];                  // cols l = 2t, 2t+1
  if (t < 128) {
    wrow[t] = sv;                       // l < 256: identity
  } else {
    int j0 = 2 * t - 256;
    float2 ov = orow[t - 128];
    float p0 = ws[WS_P + b * 256 + j0] * 0.125f;
    float p1 = ws[WS_P + b * 256 + j0 + 1] * 0.125f;
    float2 r;
    r.x = p0 * sv.x + (1.f - p0) * ov.x;
    r.y = p1 * sv.y + (1.f - p1) * ov.y;
    wrow[t] = r;
  }
}

// ---------------------------------------------------------------------------
// K6: atten FP32, float4 stores.  12288 blocks x 256 = 3.15M float4.
__global__ void k_atten(const float* __restrict__ ws, float* __restrict__ out) {
  int g4 = blockIdx.x * 256 + threadIdx.x;  // 0..3145727
  int r = g4 / 192, c = g4 - r * 192;       // r = b*512 + l, 192 float4/row
  int b = r >> 9, l = r & 511;
  int s0 = c << 2;
  float v[4] = {0.f, 0.f, 0.f, 0.f};
  if (l < 256) {
    if (l >= s0 && l < s0 + 4) v[l - s0] = 1.0f;
  } else {
    float p = ws[WS_P + b * 256 + (l - 256)] * 0.125f;
    if (l >= s0 && l < s0 + 4) v[l - s0] = p;
    int s2 = l + 256;
    if (s2 >= s0 && s2 < s0 + 4) v[s2 - s0] = 1.0f - p;
  }
  float4 val; val.x = v[0]; val.y = v[1]; val.z = v[2]; val.w = v[3];
  ((float4*)out)[g4] = val;
}

extern "C" void kernel_launch(void* const* d_in, const int* in_sizes, int n_in,
                              void* d_out, int out_size, void* d_ws, size_t ws_size,
                              hipStream_t stream) {
  const float *state = nullptr, *obs = nullptr, *Qp = nullptr;
  const float *Wq = nullptr, *Wk = nullptr, *bq = nullptr, *bk = nullptr;
  for (int i = 0; i < n_in; ++i) {
    int s = in_sizes[i];
    const float* p = (const float*)d_in[i];
    if      (s == 4194304) state = p;
    else if (s == 2097152) obs = p;
    else if (s == 131072)  Qp = p;
    else if (s == 65536)   { if (!Wq) Wq = p; else Wk = p; }
    else if (s == 256)     { if (!bq) bq = p; else bk = p; }
  }
  (void)bk;                             // cancels in the 2-way softmax
  float* out = (float*)d_out;           // FP32 output
  float* ws  = (float*)d_ws;            // 2.72 MB scratch (proven available)

  k_prep <<<66,    256, 0, stream>>>(state, obs, ws);
  k_qwpq <<<288,   256, 0, stream>>>(Qp, Wq, ws);
  k_uv   <<<2304,  256, 0, stream>>>(Wk, bq, ws);
  k_delta<<<256,   256, 0, stream>>>(state, obs, ws);
  k_ns   <<<8192,  256, 0, stream>>>(state, obs, ws, out);
  k_atten<<<12288, 256, 0, stream>>>(ws, out + 4194304);
}

// Round 19
// 158.456 us; speedup vs baseline: 25.9469x; 1.0718x over previous
//
#include <hip/hip_runtime.h>
#include <stdint.h>
#include <math.h>

// Validated semantics (r17/r18 green): printed reference, fp32 in/out.
//   p[b,j] = mean_h sigmoid(delta/sqrt(32)),
//   delta[j,b,h] = sum_e D_e*(U+V),  D_e = (s_e-mu_s)-(o_e-mu_o)
//   Folded mu (this round): sum_e D*w = sum_e (s-o)*w - ((sum s - sum o)/256)*sum_e w
//   U[h,e,j] = sum_{d in h} QwT[d,j]*Wk[d,e],  QwT = Qp[256+j]@Wq^T
//   V[b,h,e] = sum_{d in h} (Pq[b,d]+bq[d])*Wk[d,e],  Pq = pe[b]@Wq^T
//   new_state[b,e,l<256]=state; l>=256: p*s_l+(1-p)*o_{l-256}
//   atten[b,l,s]: l<256 -> 1 at s=l; else p at s=l, 1-p at s=l+256.
// 4 kernels (was 6): prologue / UV / delta(mu-inline) / fused output.

// d_ws layout (floats)
#define WS_P    0        // [32 b][256 j]  sum_h sigmoid
#define WS_QWT  8192     // [256 d][256 j]
#define WS_PQ   73728    // [32 b][256 d]
#define WS_U    81920    // [8 h][256 e][256 j]
#define WS_V    606208   // [32 b][8 h][256 e]
// end 671744 floats = 2.62 MB (ws_size >= 3.3 MB proven in r2-r4)

// ---------------------------------------------------------------------------
// K1 prologue: QwT (256 blocks), Pq with in-block pe (32), zero P (1). 289 blocks.
__global__ void k_pro(const float* __restrict__ Qp, const float* __restrict__ Wq,
                      float* __restrict__ ws) {
  __shared__ float row[256];
  int bid = blockIdx.x, t = threadIdx.x;
  if (bid < 256) {                      // QwT[d][j] = sum_e Qp[256+j][e]*Wq[d][e]
    int d = bid;
    row[t] = Wq[(size_t)d * 256 + t];
    __syncthreads();
    const float* qrow = Qp + (size_t)(256 + t) * 256;   // t = j
    float acc = 0.f;
    for (int e = 0; e < 256; ++e) acc += qrow[e] * row[e];
    ws[WS_QWT + d * 256 + t] = acc;
  } else if (bid < 288) {               // Pq[b][d] = sum_e pe[b][e]*Wq[d][e]
    int b = bid - 256;
    {                                   // pe[b][e] for e = t
      int k2 = t & ~1;                  // arange value 2k
      float div = expf((float)k2 * (-9.210340371976184f / 256.f));
      float a = (float)b * div;
      row[t] = (t & 1) ? cosf(a) : sinf(a);
    }
    __syncthreads();
    const float* wrow = Wq + (size_t)t * 256;           // t = d
    float acc = 0.f;
    for (int e = 0; e < 256; ++e) acc += row[e] * wrow[e];
    ws[WS_PQ + b * 256 + t] = acc;
  } else {                              // zero P (ws re-poisoned every call)
    for (int i = t; i < 8192; i += 256) ws[WS_P + i] = 0.f;
  }
}

// ---------------------------------------------------------------------------
// K2: U[h][e][j] and V[b][h][e].  2304 blocks x 256.
__global__ void k_uv(const float* __restrict__ Wk, const float* __restrict__ bq,
                     float* __restrict__ ws) {
  int bid = blockIdx.x, t = threadIdx.x;
  if (bid < 2048) {
    int h = bid >> 8, e = bid & 255;
    float acc = 0.f;
#pragma unroll 8
    for (int dd = 0; dd < 32; ++dd) {
      int d = h * 32 + dd;
      acc += ws[WS_QWT + d * 256 + t] * Wk[(size_t)d * 256 + e];
    }
    ws[WS_U + ((h << 8) + e) * 256 + t] = acc;
  } else {
    int idx = bid - 2048, b = idx >> 3, h = idx & 7;
    float acc = 0.f;
#pragma unroll 8
    for (int dd = 0; dd < 32; ++dd) {
      int d = h * 32 + dd;
      acc += (ws[WS_PQ + b * 256 + d] + bq[d]) * Wk[(size_t)d * 256 + t];
    }
    ws[WS_V + ((b << 3) + h) * 256 + t] = acc;
  }
}

// ---------------------------------------------------------------------------
// K3: delta with inline mu (single pass over state/obs) + sigmoid accumulate.
// 256 blocks = (b,h) x 256 threads = j.
__global__ void k_delta(const float* __restrict__ state, const float* __restrict__ obs,
                        float* __restrict__ ws) {
  int b = blockIdx.x >> 3, h = blockIdx.x & 7;
  int j = threadIdx.x;
  __shared__ float vsh[256];
  vsh[j] = ws[WS_V + ((b << 3) + h) * 256 + j];
  __syncthreads();
  const float* Uh = ws + WS_U + (h << 16);
  const float* sp = state + (size_t)b * 131072 + 256 + j;
  const float* op = obs + (size_t)b * 65536 + j;
  float a_sw = 0.f, a_w = 0.f, a_s = 0.f, a_o = 0.f;
#pragma unroll 4
  for (int e = 0; e < 256; ++e) {
    float s = sp[(size_t)e * 512];
    float o = op[(size_t)e * 256];
    float w = Uh[(e << 8) + j] + vsh[e];
    a_sw += (s - o) * w;
    a_w  += w;
    a_s  += s;
    a_o  += o;
  }
  // sum_e D*w = sum (s-o)w - mdiff*sum w,  mdiff = (sum s - sum o)/256
  float delta = a_sw - (a_s - a_o) * (1.f / 256.f) * a_w;
  float ph = 1.f / (1.f + __expf(-delta * 0.17677669529663687f)); // /sqrt(32)
  atomicAdd(&ws[WS_P + b * 256 + j], ph);
}

// ---------------------------------------------------------------------------
// K4 fused output.  20480 blocks: [0,8192) new_state rows; rest atten float4s.
__global__ void k_out(const float* __restrict__ state, const float* __restrict__ obs,
                      const float* __restrict__ ws, float* __restrict__ out) {
  int bid = blockIdx.x, t = threadIdx.x;
  if (bid < 8192) {                     // new_state row (b,e), float2/thread
    int b = bid >> 8;
    const float2* srow = (const float2*)(state + (size_t)bid * 512);
    const float2* orow = (const float2*)(obs + (size_t)bid * 256);
    float2* wrow = (float2*)(out + (size_t)bid * 512);
    float2 sv = srow[t];                // cols l = 2t, 2t+1
    if (t < 128) {
      wrow[t] = sv;                     // l < 256: identity
    } else {
      int j0 = 2 * t - 256;
      float2 ov = orow[t - 128];
      float p0 = ws[WS_P + b * 256 + j0] * 0.125f;
      float p1 = ws[WS_P + b * 256 + j0 + 1] * 0.125f;
      float2 r;
      r.x = p0 * sv.x + (1.f - p0) * ov.x;
      r.y = p1 * sv.y + (1.f - p1) * ov.y;
      wrow[t] = r;
    }
  } else {                              // atten, one float4 per thread
    int g4 = (bid - 8192) * 256 + t;    // 0..3145727
    int r = g4 / 192, c = g4 - r * 192; // r = b*512 + l
    int b = r >> 9, l = r & 511;
    int s0 = c << 2;
    float v[4] = {0.f, 0.f, 0.f, 0.f};
    if (l < 256) {
      if (l >= s0 && l < s0 + 4) v[l - s0] = 1.0f;
    } else {
      float p = ws[WS_P + b * 256 + (l - 256)] * 0.125f;
      if (l >= s0 && l < s0 + 4) v[l - s0] = p;
      int s2 = l + 256;
      if (s2 >= s0 && s2 < s0 + 4) v[s2 - s0] = 1.0f - p;
    }
    float4 val; val.x = v[0]; val.y = v[1]; val.z = v[2]; val.w = v[3];
    ((float4*)(out + 4194304))[g4] = val;
  }
}

extern "C" void kernel_launch(void* const* d_in, const int* in_sizes, int n_in,
                              void* d_out, int out_size, void* d_ws, size_t ws_size,
                              hipStream_t stream) {
  const float *state = nullptr, *obs = nullptr, *Qp = nullptr;
  const float *Wq = nullptr, *Wk = nullptr, *bq = nullptr, *bk = nullptr;
  for (int i = 0; i < n_in; ++i) {
    int s = in_sizes[i];
    const float* p = (const float*)d_in[i];
    if      (s == 4194304) state = p;
    else if (s == 2097152) obs = p;
    else if (s == 131072)  Qp = p;
    else if (s == 65536)   { if (!Wq) Wq = p; else Wk = p; }
    else if (s == 256)     { if (!bq) bq = p; else bk = p; }
  }
  (void)bk;                             // cancels in the 2-way softmax
  float* out = (float*)d_out;
  float* ws  = (float*)d_ws;

  k_pro  <<<289,   256, 0, stream>>>(Qp, Wq, ws);
  k_uv   <<<2304,  256, 0, stream>>>(Wk, bq, ws);
  k_delta<<<256,   256, 0, stream>>>(state, obs, ws);
  k_out  <<<20480, 256, 0, stream>>>(state, obs, ws, out);
}